// Round 1
// baseline (60.485 us; speedup 1.0000x reference)
//
#include <hip/hip_runtime.h>

#define TT 256
#define HH 512
#define WW 512

// K = SHARPNESS * log2(e): fold into edge constants so the inner loop uses
// raw v_exp_f32 (exp2) with no per-iteration scaling.
#define LOG2E 1.44269504088896340736f

// Per-triangle packed constants (4 x float4 = 64 B):
//  q0 = (Dy0, Dx0, C0, Dy1)
//  q1 = (Dx1, C1, Dy2, Dx2)
//  q2 = (C2, expd, expd*EPS, 0)
//  q3 = (cr, cg, cb, 0)
// where edge value (pre-scaled): E = px*Dy - py*Dx + C, and sigmoid factor is
// 1/(1+exp2(-E)).
__global__ __launch_bounds__(256) void tri_setup(
        const float* __restrict__ verts,
        const float* __restrict__ colors,
        const float* __restrict__ depth,
        float4* __restrict__ tri) {
    int t = threadIdx.x;
    const float K = 100.0f * LOG2E;

    float v0x = verts[t * 6 + 0], v0y = verts[t * 6 + 1];
    float v1x = verts[t * 6 + 2], v1y = verts[t * 6 + 3];
    float v2x = verts[t * 6 + 4], v2y = verts[t * 6 + 5];

    // edge(p, va, vb) = (px-ax)*(by-ay) - (py-ay)*(bx-ax)
    //                 = px*dy - py*dx + (ay*dx - ax*dy)
    float dx0 = v1x - v0x, dy0 = v1y - v0y;   // e0: v0 -> v1
    float dx1 = v2x - v1x, dy1 = v2y - v1y;   // e1: v1 -> v2
    float dx2 = v0x - v2x, dy2 = v0y - v2y;   // e2: v2 -> v0
    float c0 = v0y * dx0 - v0x * dy0;
    float c1 = v1y * dx1 - v1x * dy1;
    float c2 = v2y * dx2 - v2x * dy2;

    float expd = __builtin_amdgcn_exp2f(depth[t] * LOG2E);

    tri[t * 4 + 0] = make_float4(K * dy0, K * dx0, K * c0, K * dy1);
    tri[t * 4 + 1] = make_float4(K * dx1, K * c1, K * dy2, K * dx2);
    tri[t * 4 + 2] = make_float4(K * c2, expd, expd * 1e-6f, 0.0f);
    tri[t * 4 + 3] = make_float4(colors[t * 3 + 0], colors[t * 3 + 1],
                                 colors[t * 3 + 2], 0.0f);
}

__global__ __launch_bounds__(256) void tri_render(
        const float4* __restrict__ tri,
        float* __restrict__ out) {
    __shared__ float4 s_tri[TT * 4];   // 16 KiB

    int tid = threadIdx.x;
    // 256 threads load 1024 float4s.
    #pragma unroll
    for (int k = 0; k < 4; ++k)
        s_tri[tid + k * 256] = tri[tid + k * 256];
    __syncthreads();

    int pix = blockIdx.x * 256 + tid;
    int iy = pix >> 9;          // WW == 512
    int ix = pix & (WW - 1);
    const float step = 1.0f / 511.0f;   // linspace(0,1,512) step
    float px = (float)ix * step;
    float py = (float)iy * step;

    float sum = 0.0f, r = 0.0f, g = 0.0f, b = 0.0f;

    #pragma unroll 8
    for (int t = 0; t < TT; ++t) {
        float4 q0 = s_tri[t * 4 + 0];
        float4 q1 = s_tri[t * 4 + 1];
        float4 q2 = s_tri[t * 4 + 2];
        float4 q3 = s_tri[t * 4 + 3];

        float E0 = fmaf(px, q0.x, fmaf(-py, q0.y, q0.z));
        float E1 = fmaf(px, q0.w, fmaf(-py, q1.x, q1.y));
        float E2 = fmaf(px, q1.z, fmaf(-py, q1.w, q2.x));

        // prod of (1 + e^-E); overflow -> inf -> rcp -> 0 == true mask limit
        float a0 = 1.0f + __builtin_amdgcn_exp2f(-E0);
        float a1 = 1.0f + __builtin_amdgcn_exp2f(-E1);
        float a2 = 1.0f + __builtin_amdgcn_exp2f(-E2);
        float m = __builtin_amdgcn_rcpf(a0 * a1 * a2);

        // s = exp(depth)*(mask + eps)
        float s = fmaf(q2.y, m, q2.z);
        sum += s;
        r = fmaf(s, q3.x, r);
        g = fmaf(s, q3.y, g);
        b = fmaf(s, q3.z, b);
    }

    float inv = 1.0f / sum;   // exact div once per pixel
    out[pix]               = r * inv;
    out[HH * WW + pix]     = g * inv;
    out[2 * HH * WW + pix] = b * inv;
}

extern "C" void kernel_launch(void* const* d_in, const int* in_sizes, int n_in,
                              void* d_out, int out_size, void* d_ws, size_t ws_size,
                              hipStream_t stream) {
    const float* verts  = (const float*)d_in[0];
    const float* colors = (const float*)d_in[1];
    const float* depth  = (const float*)d_in[2];
    float* out = (float*)d_out;
    float4* tri = (float4*)d_ws;   // 256 * 64 B = 16 KiB scratch

    tri_setup<<<dim3(1), dim3(256), 0, stream>>>(verts, colors, depth, tri);
    tri_render<<<dim3((HH * WW) / 256), dim3(256), 0, stream>>>(tri, out);
}